// Round 1
// baseline (175.788 us; speedup 1.0000x reference)
//
#include <hip/hip_runtime.h>

// InfoNCE fwd+bwd on MI355X.
// Shapes: x (B=256, T=128, V=512) fp32, targets (B,T) int32, S=256.
// out[0] = total_loss, out[1:] = grad (B,T,V) fp32.

#define BB 256
#define TT 128
#define VV 512
#define SS 256
#define QSPLIT 4        // t-dimension split across blocks
#define TQ (TT / QSPLIT)  // 32 t per block
#define TC 8            // t per LDS chunk

// ---------------------------------------------------------------------------
// Kernel A: terms partials. grid = 256*QSPLIT blocks (b = bid&255, q = bid>>8),
// 256 threads (thread = s). partial[q][b][s] = sum over t in quarter q of
// clip(x[b,t,tgt[s,t]]).
// ---------------------------------------------------------------------------
__global__ __launch_bounds__(256) void terms_kernel(
    const float* __restrict__ x, const int* __restrict__ tgt,
    float* __restrict__ partial) {
  int bid = blockIdx.x;
  int b = bid & 255;
  int q = bid >> 8;
  int s = threadIdx.x;
  __shared__ float xch[TC * VV];  // 16 KB: 8 rows of x[b,t,:]
  float acc = 0.f;
  const float* xb = x + ((size_t)b * TT + (size_t)q * TQ) * VV;
#pragma unroll 1
  for (int c = 0; c < TQ / TC; ++c) {
    // cooperative coalesced load + clip: 8*512 floats = 1024 float4
    const float4* src = (const float4*)(xb + c * TC * VV);
    float4* dst = (float4*)xch;
#pragma unroll
    for (int k = 0; k < 4; ++k) {
      float4 v = src[s + k * 256];
      v.x = fminf(fmaxf(v.x, -30.f), 30.f);
      v.y = fminf(fmaxf(v.y, -30.f), 30.f);
      v.z = fminf(fmaxf(v.z, -30.f), 30.f);
      v.w = fminf(fmaxf(v.w, -30.f), 30.f);
      dst[s + k * 256] = v;
    }
    int t0 = q * TQ + c * TC;
    const int4 tg0 = *(const int4*)(tgt + s * TT + t0);
    const int4 tg1 = *(const int4*)(tgt + s * TT + t0 + 4);
    __syncthreads();
    acc += xch[0 * VV + tg0.x];
    acc += xch[1 * VV + tg0.y];
    acc += xch[2 * VV + tg0.z];
    acc += xch[3 * VV + tg0.w];
    acc += xch[4 * VV + tg1.x];
    acc += xch[5 * VV + tg1.y];
    acc += xch[6 * VV + tg1.z];
    acc += xch[7 * VV + tg1.w];
    __syncthreads();
  }
  // coalesced partial store: partial[q][b][s]
  partial[(((size_t)q << 8) + b) * 256 + s] = acc;
}

// ---------------------------------------------------------------------------
// Kernel B: per-row softmax/logsumexp. grid = 256 (s), 256 threads (b).
// coefT[b][s] = (b==s) - softmax(terms[s,:])[b];  losses[s] = terms[s,s]-lse.
// ---------------------------------------------------------------------------
__global__ __launch_bounds__(256) void softmax_kernel(
    const float* __restrict__ partial, float* __restrict__ coefT,
    float* __restrict__ losses) {
  int s = blockIdx.x;
  int b = threadIdx.x;
  float t = 0.f;
#pragma unroll
  for (int q = 0; q < QSPLIT; ++q)
    t += partial[(((size_t)q << 8) + b) * 256 + s];
  __shared__ float red[256];
  red[b] = t;
  __syncthreads();
#pragma unroll
  for (int off = 128; off > 0; off >>= 1) {
    if (b < off) red[b] = fmaxf(red[b], red[b + off]);
    __syncthreads();
  }
  float m = red[0];
  __syncthreads();
  float e = expf(t - m);
  red[b] = e;
  __syncthreads();
#pragma unroll
  for (int off = 128; off > 0; off >>= 1) {
    if (b < off) red[b] += red[b + off];
    __syncthreads();
  }
  float sum = red[0];
  coefT[(b << 8) + s] = (b == s ? 1.f : 0.f) - e / sum;
  if (b == s) losses[s] = t - (m + logf(sum));
}

// ---------------------------------------------------------------------------
// Kernel C: grad scatter + stream-out. grid = 256*QSPLIT (b = bid&255,
// q = bid>>8), 256 threads (thread = s). Block 0 also reduces losses -> out[0].
// grad[b,t,tgt[s,t]] += coef[s,b]; all other grad elems = 0.
// ---------------------------------------------------------------------------
__global__ __launch_bounds__(256) void grad_kernel(
    const float* __restrict__ coefT, const int* __restrict__ tgt,
    const float* __restrict__ losses, float* __restrict__ out) {
  int bid = blockIdx.x;
  int b = bid & 255;
  int q = bid >> 8;
  int s = threadIdx.x;
  __shared__ float rows[TC * VV];  // 16 KB
  if (bid == 0) {
    __shared__ double red[256];
    red[s] = (double)losses[s];
    __syncthreads();
    for (int off = 128; off > 0; off >>= 1) {
      if (s < off) red[s] += red[s + off];
      __syncthreads();
    }
    if (s == 0) out[0] = (float)red[0];
  }
  float c = coefT[(b << 8) + s];
  // grad base for this (b, quarter). NOTE: out+1 is only 4B-aligned ->
  // scalar dword stores (consecutive lanes still coalesce).
  float* gb = out + 1 + ((size_t)b * TT + (size_t)q * TQ) * VV;
#pragma unroll 1
  for (int ch = 0; ch < TQ / TC; ++ch) {
    float4* rz = (float4*)rows;
#pragma unroll
    for (int k = 0; k < 4; ++k)
      rz[s + k * 256] = make_float4(0.f, 0.f, 0.f, 0.f);
    int t0 = q * TQ + ch * TC;
    const int4 tg0 = *(const int4*)(tgt + s * TT + t0);
    const int4 tg1 = *(const int4*)(tgt + s * TT + t0 + 4);
    __syncthreads();
    atomicAdd(&rows[0 * VV + tg0.x], c);
    atomicAdd(&rows[1 * VV + tg0.y], c);
    atomicAdd(&rows[2 * VV + tg0.z], c);
    atomicAdd(&rows[3 * VV + tg0.w], c);
    atomicAdd(&rows[4 * VV + tg1.x], c);
    atomicAdd(&rows[5 * VV + tg1.y], c);
    atomicAdd(&rows[6 * VV + tg1.z], c);
    atomicAdd(&rows[7 * VV + tg1.w], c);
    __syncthreads();
    float* dsto = gb + ch * TC * VV;
#pragma unroll
    for (int k = 0; k < 16; ++k)
      dsto[s + k * 256] = rows[s + k * 256];
    __syncthreads();
  }
}

extern "C" void kernel_launch(void* const* d_in, const int* in_sizes, int n_in,
                              void* d_out, int out_size, void* d_ws, size_t ws_size,
                              hipStream_t stream) {
  const float* x = (const float*)d_in[0];
  const int* tgt = (const int*)d_in[1];
  float* out = (float*)d_out;

  float* partial = (float*)d_ws;                    // QSPLIT*256*256 floats (1 MiB)
  float* coefT = partial + QSPLIT * 256 * 256;      // 256*256 floats
  float* losses = coefT + 256 * 256;                // 256 floats

  terms_kernel<<<dim3(256 * QSPLIT), dim3(256), 0, stream>>>(x, tgt, partial);
  softmax_kernel<<<dim3(256), dim3(256), 0, stream>>>(partial, coefT, losses);
  grad_kernel<<<dim3(256 * QSPLIT), dim3(256), 0, stream>>>(coefT, tgt, losses, out);
}

// Round 5
// 165.384 us; speedup vs baseline: 1.0629x; 1.0629x over previous
//
#include <hip/hip_runtime.h>

// InfoNCE fwd+bwd on MI355X.
// x (B=256, T=128, V=512) fp32, targets (B,T) int32, S=256.
// out[0] = total_loss, out[1:] = grad (B,T,V) fp32 (16,777,217 floats).

#define TT 128
#define VV 512
#define QSPLIT 8
#define TQ (TT / QSPLIT)  // 16 t-rows per terms-block
#define TC 8              // t-rows per LDS chunk / per grad tile

typedef float f4 __attribute__((ext_vector_type(4)));  // native vec for nontemporal

// ---------------------------------------------------------------------------
// Kernel A: terms partials. grid = 2048 (b = bid&255, q = bid>>8 in 0..7),
// 256 threads (thread = s). partial[q][b][s] = sum_{t in q-slice} clip(x[b,t,tgt[s,t]])
// ---------------------------------------------------------------------------
__global__ __launch_bounds__(256) void terms_kernel(
    const float* __restrict__ x, const int* __restrict__ tgt,
    float* __restrict__ partial) {
  int bid = blockIdx.x;
  int b = bid & 255, q = bid >> 8, s = threadIdx.x;
  __shared__ __align__(16) float xch[TC * VV];  // 16 KB
  const float* xb = x + ((size_t)b * TT + q * TQ) * VV;
  // hoist this thread's 16 targets (one int4 x4, aligned)
  int4 tg[4];
#pragma unroll
  for (int k = 0; k < 4; ++k)
    tg[k] = ((const int4*)(tgt + (size_t)s * TT + q * TQ))[k];
  float acc = 0.f;
#pragma unroll
  for (int c = 0; c < 2; ++c) {
    const float4* src = (const float4*)(xb + c * TC * VV);
    float4* dst = (float4*)xch;
#pragma unroll
    for (int k = 0; k < 4; ++k) {
      float4 v = src[s + k * 256];
      v.x = fminf(fmaxf(v.x, -30.f), 30.f);
      v.y = fminf(fmaxf(v.y, -30.f), 30.f);
      v.z = fminf(fmaxf(v.z, -30.f), 30.f);
      v.w = fminf(fmaxf(v.w, -30.f), 30.f);
      dst[s + k * 256] = v;
    }
    __syncthreads();
    int4 a0 = tg[2 * c], a1 = tg[2 * c + 1];
    acc += xch[0 * VV + a0.x] + xch[1 * VV + a0.y] +
           xch[2 * VV + a0.z] + xch[3 * VV + a0.w] +
           xch[4 * VV + a1.x] + xch[5 * VV + a1.y] +
           xch[6 * VV + a1.z] + xch[7 * VV + a1.w];
    __syncthreads();
  }
  partial[(size_t)((q << 8) + b) * 256 + s] = acc;
}

// ---------------------------------------------------------------------------
// Kernel B: per-row softmax/logsumexp. grid = 256 (s), 256 threads (b).
// coefT[b][s] = (b==s) - softmax(terms[s,:])[b];  losses[s] = terms[s,s] - lse.
// ---------------------------------------------------------------------------
__global__ __launch_bounds__(256) void softmax_kernel(
    const float* __restrict__ partial, float* __restrict__ coefT,
    float* __restrict__ losses) {
  int s = blockIdx.x, b = threadIdx.x;
  int w = b >> 6, lane = b & 63;
  float t = 0.f;
#pragma unroll
  for (int q = 0; q < QSPLIT; ++q)
    t += partial[(size_t)((q << 8) + b) * 256 + s];
  // max over 256 threads: wave shfl + tiny LDS
  float m = t;
#pragma unroll
  for (int off = 32; off; off >>= 1) m = fmaxf(m, __shfl_xor(m, off));
  __shared__ float wm[4], ws[4];
  if (lane == 0) wm[w] = m;
  __syncthreads();
  m = fmaxf(fmaxf(wm[0], wm[1]), fmaxf(wm[2], wm[3]));
  float e = expf(t - m);
  float ss = e;
#pragma unroll
  for (int off = 32; off; off >>= 1) ss += __shfl_xor(ss, off);
  if (lane == 0) ws[w] = ss;
  __syncthreads();
  float sum = ws[0] + ws[1] + ws[2] + ws[3];
  coefT[(b << 8) + s] = (b == s ? 1.f : 0.f) - e / sum;
  if (b == s) losses[s] = (t - m) - logf(sum);
}

// ---------------------------------------------------------------------------
// Kernel C: grad scatter + aligned stream-out. grid = 4096 tiles, 256 threads.
// Tile j covers out[j*4096 .. j*4096+4095] (ALIGNED, loss included at out[0]):
//   slot 0   = grad flat (j*4096-1)  [always v=511 of previous row] or loss (j==0)
//   slot 1+u = grad flat (j*4096+u)
// LDS histogram has a padded slot [4096] so the 8-way scatter is branchless;
// that slot is the NEXT tile's boundary except for j==4095, where it is the
// final leftover element out[16777216].
// ---------------------------------------------------------------------------
__global__ __launch_bounds__(256) void grad_kernel(
    const float* __restrict__ coefT, const int* __restrict__ tgt,
    const float* __restrict__ losses, float* __restrict__ out) {
  int j = blockIdx.x, s = threadIdx.x;
  int w = s >> 6, lane = s & 63;
  int b = j >> 4, t0 = (j & 15) << 3;
  __shared__ __align__(16) float rows[TC * VV + 1];  // 4097 floats
  __shared__ double dred[4];
  f4* rz = (f4*)rows;
  f4 zero = {0.f, 0.f, 0.f, 0.f};
#pragma unroll
  for (int k = 0; k < 4; ++k) rz[s + k * 256] = zero;
  if (s == 0) rows[TC * VV] = 0.f;

  float c = coefT[(b << 8) + s];
  int4 tg0 = *(const int4*)(tgt + (size_t)s * TT + t0);
  int4 tg1 = *(const int4*)(tgt + (size_t)s * TT + t0 + 4);

  // boundary element (grad flat j*4096-1): row R = j*8-1, v = 511
  float bc = 0.f;
  if (j > 0) {
    int R = j * 8 - 1;
    int bh = R >> 7, th = R & 127;
    if (tgt[(size_t)s * TT + th] == VV - 1) bc = coefT[(bh << 8) + s];
  }
  double ls = 0.0;
  if (j == 0) ls = (double)losses[s];

  __syncthreads();  // zeros visible
  atomicAdd(&rows[1 + 0 * VV + tg0.x], c);
  atomicAdd(&rows[1 + 1 * VV + tg0.y], c);
  atomicAdd(&rows[1 + 2 * VV + tg0.z], c);
  atomicAdd(&rows[1 + 3 * VV + tg0.w], c);
  atomicAdd(&rows[1 + 4 * VV + tg1.x], c);
  atomicAdd(&rows[1 + 5 * VV + tg1.y], c);
  atomicAdd(&rows[1 + 6 * VV + tg1.z], c);
  atomicAdd(&rows[1 + 7 * VV + tg1.w], c);
#pragma unroll
  for (int off = 32; off; off >>= 1) bc += __shfl_xor(bc, off);
  if (j > 0 && lane == 0) atomicAdd(&rows[0], bc);
  if (j == 0) {
#pragma unroll
    for (int off = 32; off; off >>= 1) ls += __shfl_xor(ls, off);
    if (lane == 0) dred[w] = ls;
  }
  __syncthreads();  // scatter + dred done
  if (j == 0 && s == 0) rows[0] = (float)(dred[0] + dred[1] + dred[2] + dred[3]);
  __syncthreads();  // rows[0] visible

  f4* go = (f4*)(out + (size_t)j * 4096);
#pragma unroll
  for (int k = 0; k < 4; ++k)
    __builtin_nontemporal_store(rz[s + k * 256], &go[s + k * 256]);
  if (j == 4095 && s == 0) out[(size_t)4096 * 4096] = rows[TC * VV];
}

extern "C" void kernel_launch(void* const* d_in, const int* in_sizes, int n_in,
                              void* d_out, int out_size, void* d_ws, size_t ws_size,
                              hipStream_t stream) {
  const float* x = (const float*)d_in[0];
  const int* tgt = (const int*)d_in[1];
  float* out = (float*)d_out;

  float* partial = (float*)d_ws;                      // 8*256*256 floats (2 MiB)
  float* coefT = partial + QSPLIT * 256 * 256;        // 256*256 floats
  float* losses = coefT + 256 * 256;                  // 256 floats

  terms_kernel<<<dim3(2048), dim3(256), 0, stream>>>(x, tgt, partial);
  softmax_kernel<<<dim3(256), dim3(256), 0, stream>>>(partial, coefT, losses);
  grad_kernel<<<dim3(4096), dim3(256), 0, stream>>>(coefT, tgt, losses, out);
}